// Round 7
// baseline (207.070 us; speedup 1.0000x reference)
//
#include <hip/hip_runtime.h>
#include <stdint.h>
#include <stddef.h>

typedef _Float16 f16;
typedef f16 f16x4 __attribute__((ext_vector_type(4)));
typedef f16 f16x8 __attribute__((ext_vector_type(8)));
typedef float f32x4 __attribute__((ext_vector_type(4)));
typedef unsigned long long u64;
typedef unsigned int u32;

#define DEV __device__ __forceinline__

constexpr int Bb = 4, Nn = 8192, Mm = 2048, C1 = 128, C2 = 256;
constexpr int K0 = 384, CO = 256;

constexpr float Z0 = -5.12f;     // bin grid: 128 uniform bins over [-5.12, 5.12]
constexpr float BW = 0.08f;
constexpr float INVW = 12.5f;

DEV u64 minu64(u64 a, u64 b) { return a < b ? a : b; }
DEV u64 maxu64(u64 a, u64 b) { return a < b ? b : a; }

// ---------------------------------------------------------------- 0) bin known points by z (per batch)
__global__ __launch_bounds__(256) void kbin_kernel(const float* __restrict__ known,
                                                   float4* __restrict__ skey, int* __restrict__ sidxG,
                                                   int* __restrict__ binStartG)
{
  __shared__ int h[128];
  __shared__ int bs[129];
  __shared__ int cur[128];
  const int t = threadIdx.x, b = blockIdx.x;
  if (t < 128) h[t] = 0;
  __syncthreads();
  float xs[8], ys[8], zs[8]; int bn[8];
#pragma unroll
  for (int j = 0; j < 8; ++j) {
    int i = t + j * 256;
    xs[j] = known[(b * Mm + i) * 3 + 0];
    ys[j] = known[(b * Mm + i) * 3 + 1];
    zs[j] = known[(b * Mm + i) * 3 + 2];
    bn[j] = min(max((int)((zs[j] - Z0) * INVW), 0), 127);
    atomicAdd(&h[bn[j]], 1);
  }
  __syncthreads();
  if (t < 64) {                      // wave-0 exclusive scan of 128 bins
    int a = h[2 * t], c = h[2 * t + 1], sum = a + c;
#pragma unroll
    for (int off = 1; off < 64; off <<= 1) {
      int nv = __shfl_up(sum, off);
      if (t >= off) sum += nv;
    }
    int excl = sum - a - c;
    bs[2 * t] = excl; bs[2 * t + 1] = excl + a;
    if (t == 63) bs[128] = sum;
  }
  __syncthreads();
  if (t < 128) cur[t] = bs[t];
  if (t < 129) binStartG[b * 132 + t] = bs[t];
  __syncthreads();
#pragma unroll
  for (int j = 0; j < 8; ++j) {
    int i = t + j * 256;
    int slot = atomicAdd(&cur[bn[j]], 1);
    float kx = xs[j], ky = ys[j], kz = zs[j];
    float kk = __fadd_rn(__fadd_rn(__fmul_rn(kx, kx), __fmul_rn(ky, ky)), __fmul_rn(kz, kz));
    skey[b * Mm + slot] = make_float4(kx, ky, kz, kk);
    sidxG[b * Mm + slot] = i;
  }
}

// ---------------------------------------------------------------- 1) three_nn: z-pruned, np-bit-exact
// Block = 16 queries x 16 slices. Lanes keep PRIVATE top-3 u64 keys (disjoint candidate sets);
// the butterfly merge happens EXACTLY ONCE at the end (R6 bug: re-merging synchronized triples
// duplicates keys). Stop bound per round = min over lanes of lane-local k3 in key domain —
// a provable upper bound on the final global d3, so pruning is conservative-safe.
__global__ __launch_bounds__(256) void knn_pruned(
    const float* __restrict__ unknown, const float4* __restrict__ skey,
    const int* __restrict__ sidxG, const int* __restrict__ binStartG,
    int* __restrict__ oidx, float* __restrict__ ow)
{
  __shared__ float4 kpts[Mm];      // 32 KB
  __shared__ int    sidxL[Mm];     // 8 KB
  __shared__ int    bs[129];
  const int t = threadIdx.x;
  const int bx = blockIdx.x;
  const int b = bx >> 9;           // 512 blocks per batch
  const int n0 = (bx & 511) * 16;
  const int s = t & 15;            // slice
  const int q = n0 + (t >> 4);

  const float4* skb = skey + b * Mm;
  const int*    sib = sidxG + b * Mm;
#pragma unroll
  for (int j = 0; j < 8; ++j) {
    int i = t + j * 256;
    kpts[i] = skb[i];
    sidxL[i] = sib[i];
  }
  if (t < 129) bs[t] = binStartG[b * 132 + t];

  float ux = unknown[(b * Nn + q) * 3 + 0];
  float uy = unknown[(b * Nn + q) * 3 + 1];
  float uz = unknown[(b * Nn + q) * 3 + 2];
  float uu = __fadd_rn(__fadd_rn(__fmul_rn(ux, ux), __fmul_rn(uy, uy)), __fmul_rn(uz, uz));
  __syncthreads();

  u64 k1 = ~0ull, k2 = ~0ull, k3 = ~0ull;

  auto scanRange = [&](int lo, int hi) {
#pragma unroll 2
    for (int i = lo + s; i < hi; i += 16) {
      float4 kp = kpts[i];
      float dot = __fadd_rn(__fadd_rn(__fmul_rn(ux, kp.x), __fmul_rn(uy, kp.y)), __fmul_rn(uz, kp.z));
      float dd  = __fadd_rn(__fsub_rn(uu, __fadd_rn(dot, dot)), kp.w); // (uu - 2*dot) + kk, np order
      u32 bits = __float_as_uint(dd);
      u32 km = (bits & 0x80000000u) ? ~bits : (bits | 0x80000000u);    // monotone float->u32 map
      u64 key = ((u64)km << 32) | (u32)sidxL[i];
      bool c1 = key < k1, c2 = key < k2, c3 = key < k3;
      k3 = c3 ? (c2 ? k2 : key) : k3;
      k2 = c2 ? (c1 ? k1 : key) : k2;
      k1 = c1 ? key : k1;
    }
  };

  int qb = min(max((int)((uz - Z0) * INVW), 0), 127);
  int L = max(qb - 2, 0), R = min(qb + 2, 127);
  scanRange(bs[L], bs[R + 1]);

  for (int round = 0; round < 200; ++round) {
    // group-wide conservative bound: min over the 16 slices of lane-local k3 (key domain)
    u32 hk = (u32)(k3 >> 32);
#pragma unroll
    for (int msk = 1; msk <= 8; msk <<= 1) {
      u32 o = (u32)__shfl_xor((int)hk, msk);
      hk = hk < o ? hk : o;
    }
    u32 rb = (hk & 0x80000000u) ? (hk ^ 0x80000000u) : ~hk;
    float d3f = __uint_as_float(rb);                 // NaN sentinel while <3 seen -> extend
    float gL = uz - (Z0 + L * BW);
    float gR = (Z0 + (R + 1) * BW) - uz;
    bool passL = (L == 0)   || (d3f < __fmul_rn(gL, gL) * 0.999f - 1.5e-4f);
    bool passR = (R == 127) || (d3f < __fmul_rn(gR, gR) * 0.999f - 1.5e-4f);
    bool done = passL && passR;
    if (__ballot(!done) == 0ull) break;
    if (!done) {                                     // uniform within the 16-lane group
      if (!passL && L > 0)   { scanRange(bs[L - 1], bs[L]); L = L - 1; }
      if (!passR && R < 127) { scanRange(bs[R + 1], bs[R + 2]); R = R + 1; }
    }
  }

  // single butterfly merge over the 16 disjoint per-lane triples (exact stable top-3)
#pragma unroll
  for (int msk = 1; msk <= 8; msk <<= 1) {
    u64 b1 = __shfl_xor(k1, msk), b2 = __shfl_xor(k2, msk), b3 = __shfl_xor(k3, msk);
    u64 r1 = minu64(k1, b1);
    u64 r2 = minu64(maxu64(k1, b1), minu64(k2, b2));
    u64 r3 = minu64(minu64(maxu64(k2, b1), maxu64(k1, b2)), minu64(k3, b3));
    k1 = r1; k2 = r2; k3 = r3;
  }

  if (s == 0) {
    u32 h1 = (u32)(k1 >> 32), h2 = (u32)(k2 >> 32), h3 = (u32)(k3 >> 32);
    float d1 = __uint_as_float((h1 & 0x80000000u) ? (h1 ^ 0x80000000u) : ~h1);
    float d2 = __uint_as_float((h2 & 0x80000000u) ? (h2 ^ 0x80000000u) : ~h2);
    float d3 = __uint_as_float((h3 & 0x80000000u) ? (h3 ^ 0x80000000u) : ~h3);
    float t1 = sqrtf(fmaxf(d1, 0.f)), t2 = sqrtf(fmaxf(d2, 0.f)), t3 = sqrtf(fmaxf(d3, 0.f));
    float r1 = 1.f / (t1 + 1e-8f), r2 = 1.f / (t2 + 1e-8f), r3 = 1.f / (t3 + 1e-8f);
    float rs = __fadd_rn(__fadd_rn(r1, r2), r3);
    int base = (b * Nn + q) * 3;
    oidx[base + 0] = (int)(u32)k1;
    oidx[base + 1] = (int)(u32)k2;
    oidx[base + 2] = (int)(u32)k3;
    ow[base + 0] = r1 / rs; ow[base + 1] = r2 / rs; ow[base + 2] = r3 / rs;
  }
}

// ---------------------------------------------------------------- 2) known_feats (B,C2,M) f32 -> kfT (B,M,C2) f16
__global__ __launch_bounds__(256) void kft_kernel(const float* __restrict__ kf, f16* __restrict__ kfT)
{
  __shared__ f16 tile[64][72];
  const int t = threadIdx.x;
  const int m0 = blockIdx.x * 64, c0 = blockIdx.y * 64, b = blockIdx.z;
  const int lm = t & 63, row = t >> 6;
#pragma unroll
  for (int j = 0; j < 16; ++j) {
    int c = row + j * 4;
    tile[lm][c] = (f16)kf[(size_t)(b * C2 + c0 + c) * Mm + m0 + lm];
  }
  __syncthreads();
#pragma unroll
  for (int j = 0; j < 16; ++j) {
    int m = row + j * 4;
    kfT[(size_t)(b * Mm + m0 + m) * C2 + c0 + lm] = tile[m][lm];
  }
}

// ---------------------------------------------------------------- 3) weights f32 -> f16 in MFMA A-fragment order
__global__ void wrep_kernel(const float* __restrict__ W0, const float* __restrict__ W1,
                            f16* __restrict__ Af0, f16* __restrict__ Af1)
{
  int id = blockIdx.x * 256 + threadIdx.x;
  if (id < CO * K0) {
    int e = id & 7, lane = (id >> 3) & 63, mg = (id >> 9) & 15, ks = id >> 13;
    int m = mg * 16 + (lane & 15), k = ks * 32 + (lane >> 4) * 8 + e;
    Af0[id] = (f16)W0[m * K0 + k];
  }
  if (id < CO * CO) {
    int e = id & 7, lane = (id >> 3) & 63, mg = (id >> 9) & 15, ks = id >> 13;
    int m = mg * 16 + (lane & 15), k = ks * 32 + (lane >> 4) * 8 + e;
    Af1[id] = (f16)W1[m * CO + k];
  }
}

// ---------------------------------------------------------------- 4) fused interp + concat + MLP0 + MLP1 (unchanged)
__global__ __launch_bounds__(256) void mlp_fused(
    const f16* __restrict__ Af0, const f16* __restrict__ Af1,
    const f16* __restrict__ kfT, const float* __restrict__ uf,
    const int* __restrict__ idx, const float* __restrict__ wts,
    const float* __restrict__ bs0, const float* __restrict__ g0,
    const float* __restrict__ be0, const float* __restrict__ rm0, const float* __restrict__ rv0,
    const float* __restrict__ bs1, const float* __restrict__ g1,
    const float* __restrict__ be1, const float* __restrict__ rm1, const float* __restrict__ rv1,
    float* __restrict__ out)
{
  __shared__ __align__(16) char lds[53248];
  const int t = threadIdx.x;
  const int w = t >> 6, l = t & 63, lm = l & 15, qq = l >> 4;
  const int gid = blockIdx.x;
  const int b = gid >> 7, n0 = (gid & 127) * 64;

  float* bn0S = (float*)(lds + 49152);
  float* bn0H = (float*)(lds + 50176);
  float* bn1S = (float*)(lds + 51200);
  float* bn1H = (float*)(lds + 52224);
  {
    float sc0 = g0[t] / sqrtf(rv0[t] + 1e-5f);
    bn0S[t] = sc0; bn0H[t] = (bs0[t] - rm0[t]) * sc0 + be0[t];
    float sc1 = g1[t] / sqrtf(rv1[t] + 1e-5f);
    bn1S[t] = sc1; bn1H[t] = (bs1[t] - rm1[t]) * sc1 + be1[t];
  }

  {
    const int n = t >> 2, kg = t & 3;
    const int base = (b * Nn + n0 + n) * 3;
    int i0 = idx[base], i1 = idx[base + 1], i2 = idx[base + 2];
    float w0 = wts[base], w1 = wts[base + 1], w2 = wts[base + 2];
    f16 w0h = (f16)w0, w1h = (f16)w1, w2h = (f16)w2;
    f16x8 w0v = {w0h, w0h, w0h, w0h, w0h, w0h, w0h, w0h};
    f16x8 w1v = {w1h, w1h, w1h, w1h, w1h, w1h, w1h, w1h};
    f16x8 w2v = {w2h, w2h, w2h, w2h, w2h, w2h, w2h, w2h};
    const f16x8* r0 = (const f16x8*)(kfT + (size_t)(b * Mm + i0) * C2 + kg * 64);
    const f16x8* r1 = (const f16x8*)(kfT + (size_t)(b * Mm + i1) * C2 + kg * 64);
    const f16x8* r2 = (const f16x8*)(kfT + (size_t)(b * Mm + i2) * C2 + kg * 64);
#pragma unroll
    for (int j = 0; j < 8; ++j) {
      f16x8 o = r0[j] * w0v + r1[j] * w1v + r2[j] * w2v;
      int oct = kg * 8 + j;
      *(f16x8*)(lds + n * 768 + ((oct ^ (n & 7)) * 16)) = o;
    }
  }
  {
    const int n = t & 63, cb = (t >> 6) * 32;
    const float* src = uf + (size_t)(b * C1 + cb) * Nn + n0 + n;
#pragma unroll
    for (int jj = 0; jj < 4; ++jj) {
      f16x8 v;
#pragma unroll
      for (int e = 0; e < 8; ++e) v[e] = (f16)src[(size_t)(jj * 8 + e) * Nn];
      int oct = 32 + (cb >> 3) + jj;
      *(f16x8*)(lds + n * 768 + ((oct ^ (n & 7)) * 16)) = v;
    }
  }
  __syncthreads();

  f32x4 acc[4][4] = {};
  {
    f16x8 af[4];
#pragma unroll
    for (int i = 0; i < 4; ++i)
      af[i] = *(const f16x8*)(Af0 + ((size_t)(w * 4 + i) * 64 + l) * 8);
    for (int ks = 0; ks < 12; ++ks) {
      f16x8 afn[4];
      if (ks < 11) {
#pragma unroll
        for (int i = 0; i < 4; ++i)
          afn[i] = *(const f16x8*)(Af0 + ((size_t)((ks + 1) * 16 + w * 4 + i) * 64 + l) * 8);
      }
      f16x8 bf[4];
#pragma unroll
      for (int j = 0; j < 4; ++j) {
        int n = j * 16 + lm;
        bf[j] = *(const f16x8*)(lds + n * 768 + (((ks * 4 + qq) ^ (n & 7)) * 16));
      }
#pragma unroll
      for (int i = 0; i < 4; ++i)
#pragma unroll
        for (int j = 0; j < 4; ++j)
          acc[i][j] = __builtin_amdgcn_mfma_f32_16x16x32_f16(af[i], bf[j], acc[i][j], 0, 0, 0);
#pragma unroll
      for (int i = 0; i < 4; ++i) af[i] = afn[i];
    }
  }
  __syncthreads();

#pragma unroll
  for (int i = 0; i < 4; ++i) {
    const int mq = w * 64 + i * 16 + qq * 4;
    f32x4 s4 = *(const f32x4*)&bn0S[mq];
    f32x4 h4 = *(const f32x4*)&bn0H[mq];
#pragma unroll
    for (int j = 0; j < 4; ++j) {
      int n = j * 16 + lm;
      f16x4 v;
#pragma unroll
      for (int r = 0; r < 4; ++r) v[r] = (f16)fmaxf(fmaf(acc[i][j][r], s4[r], h4[r]), 0.f);
      *(f16x4*)(lds + n * 512 + (((mq >> 3) ^ (n & 7)) * 16) + (mq & 7) * 2) = v;
    }
  }
  __syncthreads();

#pragma unroll
  for (int i = 0; i < 4; ++i)
#pragma unroll
    for (int j = 0; j < 4; ++j) acc[i][j] = f32x4{0.f, 0.f, 0.f, 0.f};
  {
    f16x8 af[4];
#pragma unroll
    for (int i = 0; i < 4; ++i)
      af[i] = *(const f16x8*)(Af1 + ((size_t)(w * 4 + i) * 64 + l) * 8);
    for (int ks = 0; ks < 8; ++ks) {
      f16x8 afn[4];
      if (ks < 7) {
#pragma unroll
        for (int i = 0; i < 4; ++i)
          afn[i] = *(const f16x8*)(Af1 + ((size_t)((ks + 1) * 16 + w * 4 + i) * 64 + l) * 8);
      }
      f16x8 bf[4];
#pragma unroll
      for (int j = 0; j < 4; ++j) {
        int n = j * 16 + lm;
        bf[j] = *(const f16x8*)(lds + n * 512 + (((ks * 4 + qq) ^ (n & 7)) * 16));
      }
#pragma unroll
      for (int i = 0; i < 4; ++i)
#pragma unroll
        for (int j = 0; j < 4; ++j)
          acc[i][j] = __builtin_amdgcn_mfma_f32_16x16x32_f16(af[i], bf[j], acc[i][j], 0, 0, 0);
#pragma unroll
      for (int i = 0; i < 4; ++i) af[i] = afn[i];
    }
  }

#pragma unroll
  for (int i = 0; i < 4; ++i) {
    const int mq = w * 64 + i * 16 + qq * 4;
    f32x4 s4 = *(const f32x4*)&bn1S[mq];
    f32x4 h4 = *(const f32x4*)&bn1H[mq];
#pragma unroll
    for (int r = 0; r < 4; ++r) {
      const int m = mq + r;
#pragma unroll
      for (int j = 0; j < 4; ++j) {
        int n = j * 16 + lm;
        out[(size_t)(b * CO + m) * Nn + n0 + n] = fmaxf(fmaf(acc[i][j][r], s4[r], h4[r]), 0.f);
      }
    }
  }
}

// ---------------------------------------------------------------- launch
extern "C" void kernel_launch(void* const* d_in, const int* in_sizes, int n_in,
                              void* d_out, int out_size, void* d_ws, size_t ws_size,
                              hipStream_t stream)
{
  const float* unknown = (const float*)d_in[0];
  const float* known   = (const float*)d_in[1];
  const float* uf      = (const float*)d_in[2];
  const float* kf      = (const float*)d_in[3];
  const float* W0  = (const float*)d_in[4];
  const float* b0  = (const float*)d_in[5];
  const float* g0  = (const float*)d_in[6];
  const float* be0 = (const float*)d_in[7];
  const float* rm0 = (const float*)d_in[8];
  const float* rv0 = (const float*)d_in[9];
  const float* W1  = (const float*)d_in[10];
  const float* b1  = (const float*)d_in[11];
  const float* g1  = (const float*)d_in[12];
  const float* be1 = (const float*)d_in[13];
  const float* rm1 = (const float*)d_in[14];
  const float* rv1 = (const float*)d_in[15];

  char* ws = (char*)d_ws;
  int*    idx  = (int*)   (ws + 0);          // B*N*3 i32   = 384 KB
  float*  wts  = (float*) (ws + 393216);     // B*N*3 f32   = 384 KB
  f16*    kfT  = (f16*)   (ws + 786432);     // B*M*C2 f16  = 4 MB
  f16*    Af0  = (f16*)   (ws + 4980736);    // 256*384 f16 (fragment-order)
  f16*    Af1  = (f16*)   (ws + 5177344);    // 256*256 f16 (fragment-order)
  float4* skey = (float4*)(ws + 5308416);    // B*2048*16 B = 128 KB
  int*    sidx = (int*)   (ws + 5439488);    // B*2048*4 B  = 32 KB
  int*    bstg = (int*)   (ws + 5472256);    // B*132 i32
  float*  out  = (float*)d_out;              // (B,256,N) f32

  kbin_kernel<<<dim3(Bb), 256, 0, stream>>>(known, skey, sidx, bstg);
  knn_pruned <<<dim3(Bb * (Nn / 16)), 256, 0, stream>>>(unknown, skey, sidx, bstg, idx, wts);
  kft_kernel <<<dim3(Mm / 64, C2 / 64, Bb), 256, 0, stream>>>(kf, kfT);
  wrep_kernel<<<dim3((CO * K0 + 255) / 256), 256, 0, stream>>>(W0, W1, Af0, Af1);
  mlp_fused  <<<dim3(Bb * (Nn / 64)), 256, 0, stream>>>(
      Af0, Af1, kfT, uf, idx, wts,
      b0, g0, be0, rm0, rv0, b1, g1, be1, rm1, rv1, out);
}

// Round 8
// 167.887 us; speedup vs baseline: 1.2334x; 1.2334x over previous
//
#include <hip/hip_runtime.h>
#include <stdint.h>
#include <stddef.h>

typedef _Float16 f16;
typedef f16 f16x4 __attribute__((ext_vector_type(4)));
typedef f16 f16x8 __attribute__((ext_vector_type(8)));
typedef float f32x4 __attribute__((ext_vector_type(4)));

#define DEV __device__ __forceinline__

constexpr int Bb = 4, Nn = 8192, Mm = 2048, C1 = 128, C2 = 256;
constexpr int K0 = 384, CO = 256;

// ---------------------------------------------------------------- 1) three_nn (np-mimic fp32), split-M for occupancy
// Full O(N*M) scan, block = 16 queries x 16 slices. M scanned in two 1024-pt passes so the
// kpts buffer is 16KB -> 10 blocks/CU LDS capacity (grid gives 8) vs 5 at 32KB. Per-pair math
// uses pre-doubled query coords: fl(2a*b)=2*fl(a*b) and fl(2x+2y)=2*fl(x+y), so
// dot2 == np's 2.0*einsum BITWISE; selection therefore bit-exact vs numpy.
__global__ __launch_bounds__(256) void knn_kernel(
    const float* __restrict__ unknown, const float* __restrict__ known,
    int* __restrict__ oidx, float* __restrict__ ow)
{
  __shared__ float4 kpts[1024];      // 16 KB
  const int t  = threadIdx.x;
  const int bx = blockIdx.x;
  const int b  = bx >> 9;            // N/16 = 512 blocks per batch
  const int n0 = (bx & 511) * 16;

  const int s = t & 15;              // slice: m = it*16 + s
  const int q = n0 + (t >> 4);
  float ux = unknown[(b * Nn + q) * 3 + 0];
  float uy = unknown[(b * Nn + q) * 3 + 1];
  float uz = unknown[(b * Nn + q) * 3 + 2];
  float uu = __fadd_rn(__fadd_rn(__fmul_rn(ux, ux), __fmul_rn(uy, uy)), __fmul_rn(uz, uz));
  float ux2 = ux + ux, uy2 = uy + uy, uz2 = uz + uz;   // exact (x2 = exponent bump)

  float d1 = 1e30f, d2 = 1e30f, d3 = 1e30f;
  int   i1 = 0, i2 = 0, i3 = 0;

  for (int h = 0; h < 2; ++h) {
    __syncthreads();                 // kpts free (prev scan done)
#pragma unroll
    for (int j = 0; j < 4; ++j) {
      int m = t + j * 256;
      int gm = h * 1024 + m;
      float kx = known[(b * Mm + gm) * 3 + 0];
      float ky = known[(b * Mm + gm) * 3 + 1];
      float kz = known[(b * Mm + gm) * 3 + 2];
      float kk = __fadd_rn(__fadd_rn(__fmul_rn(kx, kx), __fmul_rn(ky, ky)), __fmul_rn(kz, kz));
      kpts[m] = make_float4(kx, ky, kz, kk);
    }
    __syncthreads();

#pragma unroll 4
    for (int it = 0; it < 64; ++it) {
      int m = it * 16 + s;
      float4 kp = kpts[m];
      // dot2 = 2*( (ux*kx + uy*ky) + uz*kz ) bitwise (scaling commutes with RN rounding)
      float dot2 = __fadd_rn(__fadd_rn(__fmul_rn(ux2, kp.x), __fmul_rn(uy2, kp.y)), __fmul_rn(uz2, kp.z));
      float dd   = __fadd_rn(__fsub_rn(uu, dot2), kp.w);  // (uu - 2*dot) + kk, np order
      int gm = h * 1024 + m;
      bool c1 = dd < d1, c2 = dd < d2, c3 = dd < d3;
      i3 = c3 ? (c2 ? i2 : gm) : i3;
      i2 = c2 ? (c1 ? i1 : gm) : i2;
      i1 = c1 ? gm : i1;
      d3 = __builtin_amdgcn_fmed3f(dd, d2, d3);
      d2 = __builtin_amdgcn_fmed3f(dd, d1, d2);
      d1 = fminf(dd, d1);
    }
  }

  // butterfly merge across the 16 slices (ties -> lower index, np-stable)
#pragma unroll
  for (int mask = 1; mask <= 8; mask <<= 1) {
    float e1 = __shfl_xor(d1, mask), e2 = __shfl_xor(d2, mask), e3 = __shfl_xor(d3, mask);
    int   j1 = __shfl_xor(i1, mask), j2 = __shfl_xor(i2, mask), j3 = __shfl_xor(i3, mask);
#pragma unroll
    for (int u = 0; u < 3; ++u) {
      float e = u == 0 ? e1 : (u == 1 ? e2 : e3);
      int   j = u == 0 ? j1 : (u == 1 ? j2 : j3);
      bool c3 = (e < d3) || (e == d3 && j < i3);
      bool c2 = (e < d2) || (e == d2 && j < i2);
      bool c1 = (e < d1) || (e == d1 && j < i1);
      d3 = c3 ? (c2 ? d2 : e) : d3;  i3 = c3 ? (c2 ? i2 : j) : i3;
      d2 = c2 ? (c1 ? d1 : e) : d2;  i2 = c2 ? (c1 ? i1 : j) : i2;
      d1 = c1 ? e : d1;              i1 = c1 ? j : i1;
    }
  }

  if (s == 0) {
    float t1 = sqrtf(fmaxf(d1, 0.f)), t2 = sqrtf(fmaxf(d2, 0.f)), t3 = sqrtf(fmaxf(d3, 0.f));
    float r1 = 1.f / (t1 + 1e-8f), r2 = 1.f / (t2 + 1e-8f), r3 = 1.f / (t3 + 1e-8f);
    float rs = __fadd_rn(__fadd_rn(r1, r2), r3);
    int base = (b * Nn + q) * 3;
    oidx[base + 0] = i1; oidx[base + 1] = i2; oidx[base + 2] = i3;
    ow[base + 0] = r1 / rs; ow[base + 1] = r2 / rs; ow[base + 2] = r3 / rs;
  }
}

// ---------------------------------------------------------------- 2) known_feats (B,C2,M) f32 -> kfT (B,M,C2) f16
__global__ __launch_bounds__(256) void kft_kernel(const float* __restrict__ kf, f16* __restrict__ kfT)
{
  __shared__ f16 tile[64][72];
  const int t = threadIdx.x;
  const int m0 = blockIdx.x * 64, c0 = blockIdx.y * 64, b = blockIdx.z;
  const int lm = t & 63, row = t >> 6;
#pragma unroll
  for (int j = 0; j < 16; ++j) {
    int c = row + j * 4;
    tile[lm][c] = (f16)kf[(size_t)(b * C2 + c0 + c) * Mm + m0 + lm];
  }
  __syncthreads();
#pragma unroll
  for (int j = 0; j < 16; ++j) {
    int m = row + j * 4;
    kfT[(size_t)(b * Mm + m0 + m) * C2 + c0 + lm] = tile[m][lm];
  }
}

// ---------------------------------------------------------------- 3) weights f32 -> f16 in MFMA A-fragment order
__global__ void wrep_kernel(const float* __restrict__ W0, const float* __restrict__ W1,
                            f16* __restrict__ Af0, f16* __restrict__ Af1)
{
  int id = blockIdx.x * 256 + threadIdx.x;
  if (id < CO * K0) {
    int e = id & 7, lane = (id >> 3) & 63, mg = (id >> 9) & 15, ks = id >> 13;
    int m = mg * 16 + (lane & 15), k = ks * 32 + (lane >> 4) * 8 + e;
    Af0[id] = (f16)W0[m * K0 + k];
  }
  if (id < CO * CO) {
    int e = id & 7, lane = (id >> 3) & 63, mg = (id >> 9) & 15, ks = id >> 13;
    int m = mg * 16 + (lane & 15), k = ks * 32 + (lane >> 4) * 8 + e;
    Af1[id] = (f16)W1[m * CO + k];
  }
}

// ---------------------------------------------------------------- 4) fused interp + concat + MLP0 + MLP1 (unchanged from R5)
__global__ __launch_bounds__(256) void mlp_fused(
    const f16* __restrict__ Af0, const f16* __restrict__ Af1,
    const f16* __restrict__ kfT, const float* __restrict__ uf,
    const int* __restrict__ idx, const float* __restrict__ wts,
    const float* __restrict__ bs0, const float* __restrict__ g0,
    const float* __restrict__ be0, const float* __restrict__ rm0, const float* __restrict__ rv0,
    const float* __restrict__ bs1, const float* __restrict__ g1,
    const float* __restrict__ be1, const float* __restrict__ rm1, const float* __restrict__ rv1,
    float* __restrict__ out)
{
  __shared__ __align__(16) char lds[53248];
  const int t = threadIdx.x;
  const int w = t >> 6, l = t & 63, lm = l & 15, qq = l >> 4;
  const int gid = blockIdx.x;
  const int b = gid >> 7, n0 = (gid & 127) * 64;

  float* bn0S = (float*)(lds + 49152);
  float* bn0H = (float*)(lds + 50176);
  float* bn1S = (float*)(lds + 51200);
  float* bn1H = (float*)(lds + 52224);
  {
    float sc0 = g0[t] / sqrtf(rv0[t] + 1e-5f);
    bn0S[t] = sc0; bn0H[t] = (bs0[t] - rm0[t]) * sc0 + be0[t];
    float sc1 = g1[t] / sqrtf(rv1[t] + 1e-5f);
    bn1S[t] = sc1; bn1H[t] = (bs1[t] - rm1[t]) * sc1 + be1[t];
  }

  {
    const int n = t >> 2, kg = t & 3;
    const int base = (b * Nn + n0 + n) * 3;
    int i0 = idx[base], i1 = idx[base + 1], i2 = idx[base + 2];
    float w0 = wts[base], w1 = wts[base + 1], w2 = wts[base + 2];
    f16 w0h = (f16)w0, w1h = (f16)w1, w2h = (f16)w2;
    f16x8 w0v = {w0h, w0h, w0h, w0h, w0h, w0h, w0h, w0h};
    f16x8 w1v = {w1h, w1h, w1h, w1h, w1h, w1h, w1h, w1h};
    f16x8 w2v = {w2h, w2h, w2h, w2h, w2h, w2h, w2h, w2h};
    const f16x8* r0 = (const f16x8*)(kfT + (size_t)(b * Mm + i0) * C2 + kg * 64);
    const f16x8* r1 = (const f16x8*)(kfT + (size_t)(b * Mm + i1) * C2 + kg * 64);
    const f16x8* r2 = (const f16x8*)(kfT + (size_t)(b * Mm + i2) * C2 + kg * 64);
#pragma unroll
    for (int j = 0; j < 8; ++j) {
      f16x8 o = r0[j] * w0v + r1[j] * w1v + r2[j] * w2v;
      int oct = kg * 8 + j;
      *(f16x8*)(lds + n * 768 + ((oct ^ (n & 7)) * 16)) = o;
    }
  }
  {
    const int n = t & 63, cb = (t >> 6) * 32;
    const float* src = uf + (size_t)(b * C1 + cb) * Nn + n0 + n;
#pragma unroll
    for (int jj = 0; jj < 4; ++jj) {
      f16x8 v;
#pragma unroll
      for (int e = 0; e < 8; ++e) v[e] = (f16)src[(size_t)(jj * 8 + e) * Nn];
      int oct = 32 + (cb >> 3) + jj;
      *(f16x8*)(lds + n * 768 + ((oct ^ (n & 7)) * 16)) = v;
    }
  }
  __syncthreads();

  f32x4 acc[4][4] = {};
  {
    f16x8 af[4];
#pragma unroll
    for (int i = 0; i < 4; ++i)
      af[i] = *(const f16x8*)(Af0 + ((size_t)(w * 4 + i) * 64 + l) * 8);
    for (int ks = 0; ks < 12; ++ks) {
      f16x8 afn[4];
      if (ks < 11) {
#pragma unroll
        for (int i = 0; i < 4; ++i)
          afn[i] = *(const f16x8*)(Af0 + ((size_t)((ks + 1) * 16 + w * 4 + i) * 64 + l) * 8);
      }
      f16x8 bf[4];
#pragma unroll
      for (int j = 0; j < 4; ++j) {
        int n = j * 16 + lm;
        bf[j] = *(const f16x8*)(lds + n * 768 + (((ks * 4 + qq) ^ (n & 7)) * 16));
      }
#pragma unroll
      for (int i = 0; i < 4; ++i)
#pragma unroll
        for (int j = 0; j < 4; ++j)
          acc[i][j] = __builtin_amdgcn_mfma_f32_16x16x32_f16(af[i], bf[j], acc[i][j], 0, 0, 0);
#pragma unroll
      for (int i = 0; i < 4; ++i) af[i] = afn[i];
    }
  }
  __syncthreads();

#pragma unroll
  for (int i = 0; i < 4; ++i) {
    const int mq = w * 64 + i * 16 + qq * 4;
    f32x4 s4 = *(const f32x4*)&bn0S[mq];
    f32x4 h4 = *(const f32x4*)&bn0H[mq];
#pragma unroll
    for (int j = 0; j < 4; ++j) {
      int n = j * 16 + lm;
      f16x4 v;
#pragma unroll
      for (int r = 0; r < 4; ++r) v[r] = (f16)fmaxf(fmaf(acc[i][j][r], s4[r], h4[r]), 0.f);
      *(f16x4*)(lds + n * 512 + (((mq >> 3) ^ (n & 7)) * 16) + (mq & 7) * 2) = v;
    }
  }
  __syncthreads();

#pragma unroll
  for (int i = 0; i < 4; ++i)
#pragma unroll
    for (int j = 0; j < 4; ++j) acc[i][j] = f32x4{0.f, 0.f, 0.f, 0.f};
  {
    f16x8 af[4];
#pragma unroll
    for (int i = 0; i < 4; ++i)
      af[i] = *(const f16x8*)(Af1 + ((size_t)(w * 4 + i) * 64 + l) * 8);
    for (int ks = 0; ks < 8; ++ks) {
      f16x8 afn[4];
      if (ks < 7) {
#pragma unroll
        for (int i = 0; i < 4; ++i)
          afn[i] = *(const f16x8*)(Af1 + ((size_t)((ks + 1) * 16 + w * 4 + i) * 64 + l) * 8);
      }
      f16x8 bf[4];
#pragma unroll
      for (int j = 0; j < 4; ++j) {
        int n = j * 16 + lm;
        bf[j] = *(const f16x8*)(lds + n * 512 + (((ks * 4 + qq) ^ (n & 7)) * 16));
      }
#pragma unroll
      for (int i = 0; i < 4; ++i)
#pragma unroll
        for (int j = 0; j < 4; ++j)
          acc[i][j] = __builtin_amdgcn_mfma_f32_16x16x32_f16(af[i], bf[j], acc[i][j], 0, 0, 0);
#pragma unroll
      for (int i = 0; i < 4; ++i) af[i] = afn[i];
    }
  }

#pragma unroll
  for (int i = 0; i < 4; ++i) {
    const int mq = w * 64 + i * 16 + qq * 4;
    f32x4 s4 = *(const f32x4*)&bn1S[mq];
    f32x4 h4 = *(const f32x4*)&bn1H[mq];
#pragma unroll
    for (int r = 0; r < 4; ++r) {
      const int m = mq + r;
#pragma unroll
      for (int j = 0; j < 4; ++j) {
        int n = j * 16 + lm;
        out[(size_t)(b * CO + m) * Nn + n0 + n] = fmaxf(fmaf(acc[i][j][r], s4[r], h4[r]), 0.f);
      }
    }
  }
}

// ---------------------------------------------------------------- launch
extern "C" void kernel_launch(void* const* d_in, const int* in_sizes, int n_in,
                              void* d_out, int out_size, void* d_ws, size_t ws_size,
                              hipStream_t stream)
{
  const float* unknown = (const float*)d_in[0];
  const float* known   = (const float*)d_in[1];
  const float* uf      = (const float*)d_in[2];
  const float* kf      = (const float*)d_in[3];
  const float* W0  = (const float*)d_in[4];
  const float* b0  = (const float*)d_in[5];
  const float* g0  = (const float*)d_in[6];
  const float* be0 = (const float*)d_in[7];
  const float* rm0 = (const float*)d_in[8];
  const float* rv0 = (const float*)d_in[9];
  const float* W1  = (const float*)d_in[10];
  const float* b1  = (const float*)d_in[11];
  const float* g1  = (const float*)d_in[12];
  const float* be1 = (const float*)d_in[13];
  const float* rm1 = (const float*)d_in[14];
  const float* rv1 = (const float*)d_in[15];

  char* ws = (char*)d_ws;
  int*   idx = (int*)  (ws + 0);          // B*N*3 i32   = 384 KB
  float* wts = (float*)(ws + 393216);     // B*N*3 f32   = 384 KB
  f16*   kfT = (f16*)  (ws + 786432);     // B*M*C2 f16  = 4 MB
  f16*   Af0 = (f16*)  (ws + 4980736);    // 256*384 f16 (fragment-order)
  f16*   Af1 = (f16*)  (ws + 5177344);    // 256*256 f16 (fragment-order)
  float* out = (float*)d_out;             // (B,256,N) f32

  knn_kernel <<<dim3(Bb * (Nn / 16)), 256, 0, stream>>>(unknown, known, idx, wts);
  kft_kernel <<<dim3(Mm / 64, C2 / 64, Bb), 256, 0, stream>>>(kf, kfT);
  wrep_kernel<<<dim3((CO * K0 + 255) / 256), 256, 0, stream>>>(W0, W1, Af0, Af1);
  mlp_fused  <<<dim3(Bb * (Nn / 64)), 256, 0, stream>>>(
      Af0, Af1, kfT, uf, idx, wts,
      b0, g0, be0, rm0, rv0, b1, g1, be1, rm1, rv1, out);
}